// Round 12
// baseline (1285.002 us; speedup 1.0000x reference)
//
#include <hip/hip_runtime.h>
#include <hip/hip_bf16.h>
#include <stdint.h>

#define Bn   16
#define Nn   4096
#define Sn   1024
#define Kn   8
#define CINn 128
#define COUTn 256

// Exact f32 squared distance, no FMA contraction: matches ((dx*dx+dy*dy)+dz*dz)
static __device__ __forceinline__ float sqdist(float ax, float ay, float az,
                                               float bx, float by, float bz) {
    float dx = __fsub_rn(ax, bx);
    float dy = __fsub_rn(ay, by);
    float dz = __fsub_rn(az, bz);
    return __fadd_rn(__fadd_rn(__fmul_rn(dx, dx), __fmul_rn(dy, dy)), __fmul_rn(dz, dz));
}

static __device__ __forceinline__ unsigned long long u64max(unsigned long long a,
                                                            unsigned long long b) {
    return a > b ? a : b;
}

// xor-swizzle a u64 across lanes within 32-lane groups (BitMode ds_swizzle)
#define SWZ_U64(key, OFF)                                                        \
    do {                                                                         \
        unsigned _lo = (unsigned)__builtin_amdgcn_ds_swizzle((int)(key), OFF);   \
        unsigned _hi = (unsigned)__builtin_amdgcn_ds_swizzle((int)((key) >> 32), OFF); \
        unsigned long long _o = ((unsigned long long)_hi << 32) | _lo;           \
        if (_o > (key)) (key) = _o;                                              \
    } while (0)

// ---------------- Kernel: farthest point sampling (UNCHANGED, validated) ----
__global__ __launch_bounds__(512) void k_fps(const float* __restrict__ xyz,
                                             float* __restrict__ out_xyz) {
    __shared__ __align__(16) float xs[Nn], ys[Nn], zs[Nn];
    __shared__ __align__(16) unsigned long long kbuf[2][512];
    const int b = blockIdx.x;
    const int tid = threadIdx.x;
    const int lane = tid & 63;
    const float* base = xyz + (size_t)b * 3 * Nn;
    for (int i = tid; i < Nn; i += 512) {
        xs[i] = base[i];
        ys[i] = base[Nn + i];
        zs[i] = base[2 * Nn + i];
    }
    __syncthreads();
    float px[8], py[8], pz[8], dist[8];
#pragma unroll
    for (int j = 0; j < 8; ++j) {
        int p = tid + j * 512;
        px[j] = xs[p]; py[j] = ys[p]; pz[j] = zs[p];
        dist[j] = 3.402823466e+38f;   // FLT_MAX, matches jnp.finfo(f32).max
    }
    int last = 0;
    if (tid == 0) {
        out_xyz[(size_t)(b * Sn) * 3 + 0] = xs[0];
        out_xyz[(size_t)(b * Sn) * 3 + 1] = ys[0];
        out_xyz[(size_t)(b * Sn) * 3 + 2] = zs[0];
    }
    for (int s = 1; s < Sn; ++s) {
        const float cx = xs[last], cy = ys[last], cz = zs[last];
        float mv = -1.0f; int mi = 0;
#pragma unroll
        for (int j = 0; j < 8; ++j) {
            float d = sqdist(px[j], py[j], pz[j], cx, cy, cz);
            float nd = fminf(dist[j], d);
            dist[j] = nd;
            if (nd > mv) { mv = nd; mi = tid + j * 512; }  // strict >: first-max wins
        }
        kbuf[s & 1][tid] =
            ((unsigned long long)__float_as_uint(mv) << 32) | (unsigned)(Nn - 1 - mi);
        __syncthreads();
        const ulonglong2* kb = (const ulonglong2*)kbuf[s & 1];
        const int l5 = lane & 31;
        ulonglong2 v0 = kb[l5];
        ulonglong2 v1 = kb[l5 + 32];
        ulonglong2 v2 = kb[l5 + 64];
        ulonglong2 v3 = kb[l5 + 96];
        ulonglong2 v4 = kb[l5 + 128];
        ulonglong2 v5 = kb[l5 + 160];
        ulonglong2 v6 = kb[l5 + 192];
        ulonglong2 v7 = kb[l5 + 224];
        unsigned long long a0 = u64max(v0.x, v0.y), a1 = u64max(v1.x, v1.y);
        unsigned long long a2 = u64max(v2.x, v2.y), a3 = u64max(v3.x, v3.y);
        unsigned long long a4 = u64max(v4.x, v4.y), a5 = u64max(v5.x, v5.y);
        unsigned long long a6 = u64max(v6.x, v6.y), a7 = u64max(v7.x, v7.y);
        unsigned long long key = u64max(u64max(u64max(a0, a1), u64max(a2, a3)),
                                        u64max(u64max(a4, a5), u64max(a6, a7)));
        SWZ_U64(key, 0x041F);   // xor 1
        SWZ_U64(key, 0x081F);   // xor 2
        SWZ_U64(key, 0x101F);   // xor 4
        SWZ_U64(key, 0x201F);   // xor 8
        SWZ_U64(key, 0x401F);   // xor 16
        const int nl = Nn - 1 - (int)(unsigned)(key & 0xFFFFFFFFull);
        if (tid == 0) {
            out_xyz[(size_t)(b * Sn + s) * 3 + 0] = xs[nl];
            out_xyz[(size_t)(b * Sn + s) * 3 + 1] = ys[nl];
            out_xyz[(size_t)(b * Sn + s) * 3 + 2] = zs[nl];
        }
        last = nl;
    }
}

// ---- Transpose: feat [B][CIN][N] -> featT [B][N][CIN], LDS 64x64 tiles -----
__global__ __launch_bounds__(256) void k_tr(const float* __restrict__ feat,
                                            float* __restrict__ featT) {
    __shared__ float t[64][65];
    const int b  = blockIdx.x >> 7;          // 16 batches
    const int ft = (blockIdx.x >> 6) & 1;    // 2 f-tiles
    const int nt = blockIdx.x & 63;          // 64 n-tiles
    const int col = threadIdx.x & 63;
    const int r0  = threadIdx.x >> 6;        // 0..3
    const float* src = feat + (size_t)b * CINn * Nn;
    float* dst = featT + (size_t)b * Nn * CINn;
#pragma unroll
    for (int i = 0; i < 16; ++i) {
        const int row = r0 + i * 4;          // f_local
        t[row][col] = src[(size_t)(ft * 64 + row) * Nn + nt * 64 + col];
    }
    __syncthreads();
#pragma unroll
    for (int i = 0; i < 16; ++i) {
        const int row = r0 + i * 4;          // n_local
        dst[(size_t)(nt * 64 + row) * CINn + ft * 64 + col] = t[col][row];
    }
}

// ---- Wave-local ball query (validated r10 ballot logic, global xyz reads) --
// Fills bslot[0..Kn-1] with first-K in-ball indices ascending, padded with
// the first. bslot is this wave's private LDS slice; no cross-wave access.
static __device__ __forceinline__ void wave_ball(const float* __restrict__ base,
                                                 float cx, float cy, float cz,
                                                 int lane, int* bslot) {
    int cnt = 0;
    int idx0 = -1;
    for (int chunk = 0; chunk < Nn / 64; ++chunk) {
        const int p = chunk * 64 + lane;
        const float d2 = sqdist(base[p], base[Nn + p], base[2 * Nn + p], cx, cy, cz);
        const bool in = (d2 <= 0.04f);             // f32(0.2*0.2)
        const unsigned long long m = __ballot(in);
        if (m != 0ull) {
            if (idx0 < 0) idx0 = chunk * 64 + __builtin_ctzll(m);
            const int rank = cnt + __popcll(m & ((1ull << lane) - 1ull));
            if (in && rank < Kn)
                bslot[rank] = p;                    // ascending by construction
            cnt += __popcll(m);
            if (cnt >= Kn) break;                   // wave-uniform
        }
    }
    if (lane < Kn && lane >= cnt)                   // pad with first index
        bslot[lane] = idx0;
}

// ---- Fused ball+feature, featT path: one WAVE per center -------------------
__global__ __launch_bounds__(256) void k_feat_fT(const float* __restrict__ xyz,
                                                 const float* __restrict__ out_xyz,
                                                 const float* __restrict__ featT,
                                                 const float* __restrict__ conv_w,
                                                 const float* __restrict__ conv_b,
                                                 const float* __restrict__ bn_g,
                                                 const float* __restrict__ bn_b,
                                                 const float* __restrict__ bn_m,
                                                 const float* __restrict__ bn_v,
                                                 float* __restrict__ out_feat) {
    __shared__ int bidx[4][Kn];
    const int wave = threadIdx.x >> 6, lane = threadIdx.x & 63;
    const int bs = blockIdx.x * 4 + wave;     // 0 .. B*S-1
    const int b  = bs >> 10;                  // Sn = 1024
    const float* base = xyz + (size_t)b * 3 * Nn;
    const float cx = out_xyz[(size_t)bs * 3 + 0];
    const float cy = out_xyz[(size_t)bs * 3 + 1];
    const float cz = out_xyz[(size_t)bs * 3 + 2];
    wave_ball(base, cx, cy, cz, lane, &bidx[wave][0]);

    int pt[Kn];
#pragma unroll
    for (int k = 0; k < Kn; ++k) pt[k] = bidx[wave][k];   // wave-internal LDS, no barrier

    const float4* ft4 = (const float4*)(featT + (size_t)b * Nn * CINn);
    const float4* cw4 = (const float4*)conv_w;   // [o][f/4]

    float acc[4][Kn];
#pragma unroll
    for (int j = 0; j < 4; ++j)
#pragma unroll
        for (int k = 0; k < Kn; ++k) acc[j][k] = 0.0f;

    for (int f4 = 0; f4 < CINn / 4; ++f4) {
        float4 w[4];
#pragma unroll
        for (int j = 0; j < 4; ++j)
            w[j] = cw4[(size_t)(lane + 64 * j) * (CINn / 4) + f4];
        float4 fv[Kn];
#pragma unroll
        for (int k = 0; k < Kn; ++k)
            fv[k] = ft4[(size_t)pt[k] * (CINn / 4) + f4];   // wave-uniform 16B
#pragma unroll
        for (int c = 0; c < 4; ++c) {
#pragma unroll
            for (int j = 0; j < 4; ++j) {
                const float wc = ((const float*)&w[j])[c];
#pragma unroll
                for (int k = 0; k < Kn; ++k)
                    acc[j][k] += ((const float*)&fv[k])[c] * wc;
            }
        }
    }

#pragma unroll
    for (int j = 0; j < 4; ++j) {
        const int o = lane + 64 * j;
        const float bias = conv_b[o];
        const float gg = bn_g[o], be = bn_b[o], mn = bn_m[o], vr = bn_v[o];
        const float inv = sqrtf(vr + 1e-5f);
        float mx = -3.402823466e+38f;
#pragma unroll
        for (int k = 0; k < Kn; ++k) {
            float z = acc[j][k] + bias;
            float y = gg * (z - mn) / inv + be;
            y = fmaxf(y, 0.0f);              // ReLU before max, literal order
            mx = fmaxf(mx, y);
        }
        out_feat[(size_t)bs * COUTn + o] = mx;
    }
}

// ---- Fused ball+feature, direct-layout fallback (validated gather text) ----
__global__ __launch_bounds__(256) void k_feat_fD(const float* __restrict__ xyz,
                                                 const float* __restrict__ out_xyz,
                                                 const float* __restrict__ feat,
                                                 const float* __restrict__ conv_w,
                                                 const float* __restrict__ conv_b,
                                                 const float* __restrict__ bn_g,
                                                 const float* __restrict__ bn_b,
                                                 const float* __restrict__ bn_m,
                                                 const float* __restrict__ bn_v,
                                                 float* __restrict__ out_feat) {
    __shared__ int bidx[4][Kn];
    const int wave = threadIdx.x >> 6, lane = threadIdx.x & 63;
    const int bs = blockIdx.x * 4 + wave;
    const int b  = bs >> 10;
    const float* base = xyz + (size_t)b * 3 * Nn;
    const float cx = out_xyz[(size_t)bs * 3 + 0];
    const float cy = out_xyz[(size_t)bs * 3 + 1];
    const float cz = out_xyz[(size_t)bs * 3 + 2];
    wave_ball(base, cx, cy, cz, lane, &bidx[wave][0]);

    int pt[Kn];
#pragma unroll
    for (int k = 0; k < Kn; ++k) pt[k] = bidx[wave][k];

    const float* fb = feat + (size_t)b * CINn * Nn;
    const float4* cw4 = (const float4*)conv_w;

    float acc[4][Kn];
#pragma unroll
    for (int j = 0; j < 4; ++j)
#pragma unroll
        for (int k = 0; k < Kn; ++k) acc[j][k] = 0.0f;

    for (int f4 = 0; f4 < CINn / 4; ++f4) {
        float4 w[4];
#pragma unroll
        for (int j = 0; j < 4; ++j)
            w[j] = cw4[(size_t)(lane + 64 * j) * (CINn / 4) + f4];
#pragma unroll
        for (int c = 0; c < 4; ++c) {
            const float* frc = fb + (size_t)(f4 * 4 + c) * Nn;
            float fv[Kn];
#pragma unroll
            for (int k = 0; k < Kn; ++k) fv[k] = frc[pt[k]];
#pragma unroll
            for (int j = 0; j < 4; ++j) {
                const float wc = ((const float*)&w[j])[c];
#pragma unroll
                for (int k = 0; k < Kn; ++k) acc[j][k] += fv[k] * wc;
            }
        }
    }

#pragma unroll
    for (int j = 0; j < 4; ++j) {
        const int o = lane + 64 * j;
        const float bias = conv_b[o];
        const float g = bn_g[o], be = bn_b[o], mn = bn_m[o], vr = bn_v[o];
        const float inv = sqrtf(vr + 1e-5f);
        float mx = -3.402823466e+38f;
#pragma unroll
        for (int k = 0; k < Kn; ++k) {
            float z = acc[j][k] + bias;
            float y = g * (z - mn) / inv + be;
            y = fmaxf(y, 0.0f);
            mx = fmaxf(mx, y);
        }
        out_feat[(size_t)bs * COUTn + o] = mx;
    }
}

extern "C" void kernel_launch(void* const* d_in, const int* in_sizes, int n_in,
                              void* d_out, int out_size, void* d_ws, size_t ws_size,
                              hipStream_t stream) {
    const float* xyz    = (const float*)d_in[0];
    const float* feat   = (const float*)d_in[1];
    const float* conv_w = (const float*)d_in[2];
    const float* conv_b = (const float*)d_in[3];
    const float* bn_g   = (const float*)d_in[4];
    const float* bn_b   = (const float*)d_in[5];
    const float* bn_m   = (const float*)d_in[6];
    const float* bn_v   = (const float*)d_in[7];

    float* out_xyz  = (float*)d_out;
    float* out_feat = out_xyz + (size_t)Bn * Sn * 3;

    float* featT = (float*)d_ws;   // 32 MB at offset 0
    const bool haveT = ws_size >= (size_t)Bn * Nn * CINn * 4;

    if (haveT)
        k_tr<<<dim3(Bn * 128), dim3(256), 0, stream>>>(feat, featT);

    k_fps<<<dim3(Bn), dim3(512), 0, stream>>>(xyz, out_xyz);

    if (haveT)
        k_feat_fT<<<dim3(Bn * Sn / 4), dim3(256), 0, stream>>>(xyz, out_xyz, featT,
                                                               conv_w, conv_b,
                                                               bn_g, bn_b, bn_m, bn_v,
                                                               out_feat);
    else
        k_feat_fD<<<dim3(Bn * Sn / 4), dim3(256), 0, stream>>>(xyz, out_xyz, feat,
                                                               conv_w, conv_b,
                                                               bn_g, bn_b, bn_m, bn_v,
                                                               out_feat);
}

// Round 13
// 1074.025 us; speedup vs baseline: 1.1964x; 1.1964x over previous
//
#include <hip/hip_runtime.h>
#include <hip/hip_bf16.h>
#include <stdint.h>

#define Bn   16
#define Nn   4096
#define Sn   1024
#define Kn   8
#define CINn 128
#define COUTn 256

// Exact f32 squared distance, no FMA contraction: matches ((dx*dx+dy*dy)+dz*dz)
static __device__ __forceinline__ float sqdist(float ax, float ay, float az,
                                               float bx, float by, float bz) {
    float dx = __fsub_rn(ax, bx);
    float dy = __fsub_rn(ay, by);
    float dz = __fsub_rn(az, bz);
    return __fadd_rn(__fadd_rn(__fmul_rn(dx, dx), __fmul_rn(dy, dy)), __fmul_rn(dz, dz));
}

static __device__ __forceinline__ unsigned long long u64max(unsigned long long a,
                                                            unsigned long long b) {
    return a > b ? a : b;
}

// xor-swizzle a u64 across lanes within 32-lane groups (BitMode ds_swizzle)
#define SWZ_U64(key, OFF)                                                        \
    do {                                                                         \
        unsigned _lo = (unsigned)__builtin_amdgcn_ds_swizzle((int)(key), OFF);   \
        unsigned _hi = (unsigned)__builtin_amdgcn_ds_swizzle((int)((key) >> 32), OFF); \
        unsigned long long _o = ((unsigned long long)_hi << 32) | _lo;           \
        if (_o > (key)) (key) = _o;                                              \
    } while (0)

// ---------------- Kernel: farthest point sampling (UNCHANGED, validated) ----
__global__ __launch_bounds__(512) void k_fps(const float* __restrict__ xyz,
                                             float* __restrict__ out_xyz) {
    __shared__ __align__(16) float xs[Nn], ys[Nn], zs[Nn];
    __shared__ __align__(16) unsigned long long kbuf[2][512];
    const int b = blockIdx.x;
    const int tid = threadIdx.x;
    const int lane = tid & 63;
    const float* base = xyz + (size_t)b * 3 * Nn;
    for (int i = tid; i < Nn; i += 512) {
        xs[i] = base[i];
        ys[i] = base[Nn + i];
        zs[i] = base[2 * Nn + i];
    }
    __syncthreads();
    float px[8], py[8], pz[8], dist[8];
#pragma unroll
    for (int j = 0; j < 8; ++j) {
        int p = tid + j * 512;
        px[j] = xs[p]; py[j] = ys[p]; pz[j] = zs[p];
        dist[j] = 3.402823466e+38f;   // FLT_MAX, matches jnp.finfo(f32).max
    }
    int last = 0;
    if (tid == 0) {
        out_xyz[(size_t)(b * Sn) * 3 + 0] = xs[0];
        out_xyz[(size_t)(b * Sn) * 3 + 1] = ys[0];
        out_xyz[(size_t)(b * Sn) * 3 + 2] = zs[0];
    }
    for (int s = 1; s < Sn; ++s) {
        const float cx = xs[last], cy = ys[last], cz = zs[last];
        float mv = -1.0f; int mi = 0;
#pragma unroll
        for (int j = 0; j < 8; ++j) {
            float d = sqdist(px[j], py[j], pz[j], cx, cy, cz);
            float nd = fminf(dist[j], d);
            dist[j] = nd;
            if (nd > mv) { mv = nd; mi = tid + j * 512; }  // strict >: first-max wins
        }
        kbuf[s & 1][tid] =
            ((unsigned long long)__float_as_uint(mv) << 32) | (unsigned)(Nn - 1 - mi);
        __syncthreads();
        const ulonglong2* kb = (const ulonglong2*)kbuf[s & 1];
        const int l5 = lane & 31;
        ulonglong2 v0 = kb[l5];
        ulonglong2 v1 = kb[l5 + 32];
        ulonglong2 v2 = kb[l5 + 64];
        ulonglong2 v3 = kb[l5 + 96];
        ulonglong2 v4 = kb[l5 + 128];
        ulonglong2 v5 = kb[l5 + 160];
        ulonglong2 v6 = kb[l5 + 192];
        ulonglong2 v7 = kb[l5 + 224];
        unsigned long long a0 = u64max(v0.x, v0.y), a1 = u64max(v1.x, v1.y);
        unsigned long long a2 = u64max(v2.x, v2.y), a3 = u64max(v3.x, v3.y);
        unsigned long long a4 = u64max(v4.x, v4.y), a5 = u64max(v5.x, v5.y);
        unsigned long long a6 = u64max(v6.x, v6.y), a7 = u64max(v7.x, v7.y);
        unsigned long long key = u64max(u64max(u64max(a0, a1), u64max(a2, a3)),
                                        u64max(u64max(a4, a5), u64max(a6, a7)));
        SWZ_U64(key, 0x041F);   // xor 1
        SWZ_U64(key, 0x081F);   // xor 2
        SWZ_U64(key, 0x101F);   // xor 4
        SWZ_U64(key, 0x201F);   // xor 8
        SWZ_U64(key, 0x401F);   // xor 16
        const int nl = Nn - 1 - (int)(unsigned)(key & 0xFFFFFFFFull);
        if (tid == 0) {
            out_xyz[(size_t)(b * Sn + s) * 3 + 0] = xs[nl];
            out_xyz[(size_t)(b * Sn + s) * 3 + 1] = ys[nl];
            out_xyz[(size_t)(b * Sn + s) * 3 + 2] = zs[nl];
        }
        last = nl;
    }
}

// ---- Wave-local ball query (validated r10/r12 ballot logic) ----------------
static __device__ __forceinline__ void wave_ball(const float* __restrict__ base,
                                                 float cx, float cy, float cz,
                                                 int lane, int* bslot) {
    int cnt = 0;
    int idx0 = -1;
    for (int chunk = 0; chunk < Nn / 64; ++chunk) {
        const int p = chunk * 64 + lane;
        const float d2 = sqdist(base[p], base[Nn + p], base[2 * Nn + p], cx, cy, cz);
        const bool in = (d2 <= 0.04f);             // f32(0.2*0.2)
        const unsigned long long m = __ballot(in);
        if (m != 0ull) {
            if (idx0 < 0) idx0 = chunk * 64 + __builtin_ctzll(m);
            const int rank = cnt + __popcll(m & ((1ull << lane) - 1ull));
            if (in && rank < Kn)
                bslot[rank] = p;                    // ascending by construction
            cnt += __popcll(m);
            if (cnt >= Kn) break;                   // wave-uniform
        }
    }
    if (lane < Kn && lane >= cnt)                   // pad with first index
        bslot[lane] = idx0;
}

// ---- Fused ball + conv + BN + ReLU + maxK: one WAVE per center -------------
// 512 threads = 8 waves = 8 centers/block. conv_w staged ONCE per block in
// LDS as Wlds[f][o] (bank-conflict-free b32 reads, lane-consecutive o).
// Batch = blockIdx & 15 -> all 128 blocks of a batch land on XCD (b & 7),
// keeping that batch's 2MB feat slice in one XCD L2.
// Per-accumulator FP order identical to validated r9-r12 kernels.
__global__ __launch_bounds__(512) void k_feat(const float* __restrict__ xyz,
                                              const float* __restrict__ out_xyz,
                                              const float* __restrict__ feat,
                                              const float* __restrict__ conv_w,
                                              const float* __restrict__ conv_b,
                                              const float* __restrict__ bn_g,
                                              const float* __restrict__ bn_b,
                                              const float* __restrict__ bn_m,
                                              const float* __restrict__ bn_v,
                                              float* __restrict__ out_feat) {
    __shared__ float Wlds[CINn][COUTn + 1];   // [f][o], pad breaks staging conflicts
    __shared__ int bidx[8][Kn];
    const int tid = threadIdx.x;
    const int wave = tid >> 6, lane = tid & 63;
    const int b  = blockIdx.x & 15;                 // XCD-grouped batches
    const int c0 = (blockIdx.x >> 4) * 8;
    const int bs = b * Sn + c0 + wave;

    // stage W: coalesced float4 reads, transpose into [f][o]
    {
        const float4* cw4 = (const float4*)conv_w;  // [o][f/4]
#pragma unroll
        for (int i = 0; i < 16; ++i) {
            const int idx = tid + 512 * i;          // 0..8191
            const float4 v = cw4[idx];
            const int o = idx >> 5, f4 = idx & 31;
            Wlds[f4 * 4 + 0][o] = v.x;
            Wlds[f4 * 4 + 1][o] = v.y;
            Wlds[f4 * 4 + 2][o] = v.z;
            Wlds[f4 * 4 + 3][o] = v.w;
        }
    }

    // ball query (wave-local; bidx slice private to this wave)
    const float* base = xyz + (size_t)b * 3 * Nn;
    const float cx = out_xyz[(size_t)bs * 3 + 0];
    const float cy = out_xyz[(size_t)bs * 3 + 1];
    const float cz = out_xyz[(size_t)bs * 3 + 2];
    wave_ball(base, cx, cy, cz, lane, &bidx[wave][0]);

    int pt[Kn];
#pragma unroll
    for (int k = 0; k < Kn; ++k) pt[k] = bidx[wave][k];   // wave-internal, no barrier

    __syncthreads();   // Wlds staged by all waves

    const float* fb = feat + (size_t)b * CINn * Nn;
    float acc[4][Kn];
#pragma unroll
    for (int j = 0; j < 4; ++j)
#pragma unroll
        for (int k = 0; k < Kn; ++k) acc[j][k] = 0.0f;

    for (int f4 = 0; f4 < CINn / 4; ++f4) {
#pragma unroll
        for (int c = 0; c < 4; ++c) {
            const float* frc = fb + (size_t)(f4 * 4 + c) * Nn;
            float fv[Kn];
#pragma unroll
            for (int k = 0; k < Kn; ++k) fv[k] = frc[pt[k]];   // broadcast, 1 line
#pragma unroll
            for (int j = 0; j < 4; ++j) {
                const float wc = Wlds[f4 * 4 + c][lane + 64 * j];  // conflict-free
#pragma unroll
                for (int k = 0; k < Kn; ++k) acc[j][k] += fv[k] * wc;
            }
        }
    }

    // epilogue: identical math/order to the validated kernels
#pragma unroll
    for (int j = 0; j < 4; ++j) {
        const int o = lane + 64 * j;
        const float bias = conv_b[o];
        const float g = bn_g[o], be = bn_b[o], mn = bn_m[o], vr = bn_v[o];
        const float inv = sqrtf(vr + 1e-5f);
        float mx = -3.402823466e+38f;
#pragma unroll
        for (int k = 0; k < Kn; ++k) {
            float z = acc[j][k] + bias;
            float y = g * (z - mn) / inv + be;
            y = fmaxf(y, 0.0f);              // ReLU before max, literal order
            mx = fmaxf(mx, y);
        }
        out_feat[(size_t)bs * COUTn + o] = mx;
    }
}

extern "C" void kernel_launch(void* const* d_in, const int* in_sizes, int n_in,
                              void* d_out, int out_size, void* d_ws, size_t ws_size,
                              hipStream_t stream) {
    const float* xyz    = (const float*)d_in[0];
    const float* feat   = (const float*)d_in[1];
    const float* conv_w = (const float*)d_in[2];
    const float* conv_b = (const float*)d_in[3];
    const float* bn_g   = (const float*)d_in[4];
    const float* bn_b   = (const float*)d_in[5];
    const float* bn_m   = (const float*)d_in[6];
    const float* bn_v   = (const float*)d_in[7];

    float* out_xyz  = (float*)d_out;
    float* out_feat = out_xyz + (size_t)Bn * Sn * 3;

    // no workspace usage
    k_fps <<<dim3(Bn),           dim3(512), 0, stream>>>(xyz, out_xyz);
    k_feat<<<dim3(Bn * Sn / 8),  dim3(512), 0, stream>>>(xyz, out_xyz, feat,
                                                         conv_w, conv_b,
                                                         bn_g, bn_b, bn_m, bn_v,
                                                         out_feat);
}

// Round 14
// 829.205 us; speedup vs baseline: 1.5497x; 1.2952x over previous
//
#include <hip/hip_runtime.h>
#include <hip/hip_bf16.h>
#include <stdint.h>

#define Bn   16
#define Nn   4096
#define Sn   1024
#define Kn   8
#define CINn 128
#define COUTn 256

// Exact f32 squared distance, no FMA contraction: matches ((dx*dx+dy*dy)+dz*dz)
static __device__ __forceinline__ float sqdist(float ax, float ay, float az,
                                               float bx, float by, float bz) {
    float dx = __fsub_rn(ax, bx);
    float dy = __fsub_rn(ay, by);
    float dz = __fsub_rn(az, bz);
    return __fadd_rn(__fadd_rn(__fmul_rn(dx, dx), __fmul_rn(dy, dy)), __fmul_rn(dz, dz));
}

static __device__ __forceinline__ unsigned long long u64max(unsigned long long a,
                                                            unsigned long long b) {
    return a > b ? a : b;
}

// Wave-wide u64 max via DPP (VALU pipe, no LDS): row_shr 1/2/4/8 then
// row_bcast:15 / row_bcast:31, old = own key (identity for max), then
// readlane(63) broadcasts the result to all lanes.
#define DPP_MAX_LEVEL(lo, hi, CTRL)                                              \
    do {                                                                         \
        int _olo = __builtin_amdgcn_update_dpp(lo, lo, CTRL, 0xF, 0xF, false);   \
        int _ohi = __builtin_amdgcn_update_dpp(hi, hi, CTRL, 0xF, 0xF, false);   \
        unsigned long long _o = ((unsigned long long)(unsigned)_ohi << 32) |     \
                                (unsigned)_olo;                                  \
        unsigned long long _k = ((unsigned long long)(unsigned)hi << 32) |       \
                                (unsigned)lo;                                    \
        if (_o > _k) { lo = _olo; hi = _ohi; }                                   \
    } while (0)

static __device__ __forceinline__ unsigned long long wave_max_u64(unsigned long long key) {
    int lo = (int)(unsigned)(key & 0xFFFFFFFFull);
    int hi = (int)(unsigned)(key >> 32);
    DPP_MAX_LEVEL(lo, hi, 0x111);   // row_shr:1
    DPP_MAX_LEVEL(lo, hi, 0x112);   // row_shr:2
    DPP_MAX_LEVEL(lo, hi, 0x114);   // row_shr:4
    DPP_MAX_LEVEL(lo, hi, 0x118);   // row_shr:8
    DPP_MAX_LEVEL(lo, hi, 0x142);   // row_bcast:15
    DPP_MAX_LEVEL(lo, hi, 0x143);   // row_bcast:31
    unsigned flo = (unsigned)__builtin_amdgcn_readlane(lo, 63);
    unsigned fhi = (unsigned)__builtin_amdgcn_readlane(hi, 63);
    return ((unsigned long long)fhi << 32) | flo;
}

// ---------------- Kernel: farthest point sampling ---------------------------
// Exact argmax/tie-break semantics (validated r6-r13 via output 0).
// 256 threads, 16 pts/thread. Per step: per-thread argmax -> u64 key ->
// DPP wave reduce (VALU) -> 4 wave-maxes in LDS (double-buffered, ONE
// barrier) -> broadcast read + 3 u64max -> next center.
__global__ __launch_bounds__(256) void k_fps(const float* __restrict__ xyz,
                                             float* __restrict__ out_xyz) {
    __shared__ __align__(16) float xs[Nn], ys[Nn], zs[Nn];
    __shared__ __align__(16) unsigned long long gbuf[2][4];
    const int b = blockIdx.x;
    const int tid = threadIdx.x;
    const int wid = tid >> 6, lane = tid & 63;
    const float* base = xyz + (size_t)b * 3 * Nn;
    for (int i = tid; i < Nn; i += 256) {
        xs[i] = base[i];
        ys[i] = base[Nn + i];
        zs[i] = base[2 * Nn + i];
    }
    __syncthreads();
    float px[16], py[16], pz[16], dist[16];
#pragma unroll
    for (int j = 0; j < 16; ++j) {
        int p = tid + j * 256;
        px[j] = xs[p]; py[j] = ys[p]; pz[j] = zs[p];
        dist[j] = 3.402823466e+38f;   // FLT_MAX, matches jnp.finfo(f32).max
    }
    int last = 0;
    if (tid == 0) {
        out_xyz[(size_t)(b * Sn) * 3 + 0] = xs[0];
        out_xyz[(size_t)(b * Sn) * 3 + 1] = ys[0];
        out_xyz[(size_t)(b * Sn) * 3 + 2] = zs[0];
    }
    for (int s = 1; s < Sn; ++s) {
        const float cx = xs[last], cy = ys[last], cz = zs[last];
        float mv = -1.0f; int mi = 0;
#pragma unroll
        for (int j = 0; j < 16; ++j) {
            float d = sqdist(px[j], py[j], pz[j], cx, cy, cz);
            float nd = fminf(dist[j], d);
            dist[j] = nd;
            if (nd > mv) { mv = nd; mi = tid + j * 256; }  // strict >: first-max wins
        }
        // pack: dist bits high (dist>=0 so f32 bit order == value order),
        // (N-1-idx) low so u64-max tie-breaks to the SMALLEST index.
        unsigned long long key =
            ((unsigned long long)__float_as_uint(mv) << 32) | (unsigned)(Nn - 1 - mi);
        key = wave_max_u64(key);            // all lanes hold wave max
        if (lane == 0) gbuf[s & 1][wid] = key;
        __syncthreads();
        const ulonglong2 g0 = *(const ulonglong2*)&gbuf[s & 1][0];
        const ulonglong2 g1 = *(const ulonglong2*)&gbuf[s & 1][2];
        key = u64max(u64max(g0.x, g0.y), u64max(g1.x, g1.y));
        const int nl = Nn - 1 - (int)(unsigned)(key & 0xFFFFFFFFull);
        if (tid == 0) {
            out_xyz[(size_t)(b * Sn + s) * 3 + 0] = xs[nl];
            out_xyz[(size_t)(b * Sn + s) * 3 + 1] = ys[nl];
            out_xyz[(size_t)(b * Sn + s) * 3 + 2] = zs[nl];
        }
        last = nl;
        // no second barrier: next step writes the OTHER gbuf half; this half
        // is rewritten only after the s+1 barrier, which every wave reaches
        // after completing this step's reads (program order) — r9-validated.
    }
}

// ---- Wave-local ball query (validated r10/r12/r13 ballot logic) ------------
static __device__ __forceinline__ void wave_ball(const float* __restrict__ base,
                                                 float cx, float cy, float cz,
                                                 int lane, int* bslot) {
    int cnt = 0;
    int idx0 = -1;
    for (int chunk = 0; chunk < Nn / 64; ++chunk) {
        const int p = chunk * 64 + lane;
        const float d2 = sqdist(base[p], base[Nn + p], base[2 * Nn + p], cx, cy, cz);
        const bool in = (d2 <= 0.04f);             // f32(0.2*0.2)
        const unsigned long long m = __ballot(in);
        if (m != 0ull) {
            if (idx0 < 0) idx0 = chunk * 64 + __builtin_ctzll(m);
            const int rank = cnt + __popcll(m & ((1ull << lane) - 1ull));
            if (in && rank < Kn)
                bslot[rank] = p;                    // ascending by construction
            cnt += __popcll(m);
            if (cnt >= Kn) break;                   // wave-uniform
        }
    }
    if (lane < Kn && lane >= cnt)                   // pad with first index
        bslot[lane] = idx0;
}

// ---- Fused ball + conv + BN + ReLU + maxK: one WAVE per center -------------
// 1024 threads = 16 waves = 16 centers/block (2x waves/CU vs r13 for latency
// hiding at 1 block/CU). conv_w staged once per block in LDS [f][o].
// Batch = blockIdx & 15 -> all 64 blocks of a batch on XCD (b & 7).
// Per-accumulator FP order identical to validated r9-r13 kernels.
__global__ __launch_bounds__(1024) void k_feat(const float* __restrict__ xyz,
                                               const float* __restrict__ out_xyz,
                                               const float* __restrict__ feat,
                                               const float* __restrict__ conv_w,
                                               const float* __restrict__ conv_b,
                                               const float* __restrict__ bn_g,
                                               const float* __restrict__ bn_b,
                                               const float* __restrict__ bn_m,
                                               const float* __restrict__ bn_v,
                                               float* __restrict__ out_feat) {
    __shared__ float Wlds[CINn][COUTn + 1];   // [f][o], pad breaks staging conflicts
    __shared__ int bidx[16][Kn];
    const int tid = threadIdx.x;
    const int wave = tid >> 6, lane = tid & 63;
    const int b  = blockIdx.x & 15;                 // XCD-grouped batches
    const int c0 = (blockIdx.x >> 4) * 16;
    const int bs = b * Sn + c0 + wave;

    // stage W: coalesced float4 reads, transpose into [f][o]
    {
        const float4* cw4 = (const float4*)conv_w;  // [o][f/4]
#pragma unroll
        for (int i = 0; i < 8; ++i) {
            const int idx = tid + 1024 * i;         // 0..8191
            const float4 v = cw4[idx];
            const int o = idx >> 5, f4 = idx & 31;
            Wlds[f4 * 4 + 0][o] = v.x;
            Wlds[f4 * 4 + 1][o] = v.y;
            Wlds[f4 * 4 + 2][o] = v.z;
            Wlds[f4 * 4 + 3][o] = v.w;
        }
    }

    // ball query (wave-local; bidx slice private to this wave)
    const float* base = xyz + (size_t)b * 3 * Nn;
    const float cx = out_xyz[(size_t)bs * 3 + 0];
    const float cy = out_xyz[(size_t)bs * 3 + 1];
    const float cz = out_xyz[(size_t)bs * 3 + 2];
    wave_ball(base, cx, cy, cz, lane, &bidx[wave][0]);

    int pt[Kn];
#pragma unroll
    for (int k = 0; k < Kn; ++k) pt[k] = bidx[wave][k];   // wave-internal, no barrier

    __syncthreads();   // Wlds staged by all waves

    const float* fb = feat + (size_t)b * CINn * Nn;
    float acc[4][Kn];
#pragma unroll
    for (int j = 0; j < 4; ++j)
#pragma unroll
        for (int k = 0; k < Kn; ++k) acc[j][k] = 0.0f;

    for (int f4 = 0; f4 < CINn / 4; ++f4) {
#pragma unroll
        for (int c = 0; c < 4; ++c) {
            const float* frc = fb + (size_t)(f4 * 4 + c) * Nn;
            float fv[Kn];
#pragma unroll
            for (int k = 0; k < Kn; ++k) fv[k] = frc[pt[k]];   // broadcast, 1 line
#pragma unroll
            for (int j = 0; j < 4; ++j) {
                const float wc = Wlds[f4 * 4 + c][lane + 64 * j];  // conflict-free
#pragma unroll
                for (int k = 0; k < Kn; ++k) acc[j][k] += fv[k] * wc;
            }
        }
    }

    // epilogue: identical math/order to the validated kernels
#pragma unroll
    for (int j = 0; j < 4; ++j) {
        const int o = lane + 64 * j;
        const float bias = conv_b[o];
        const float g = bn_g[o], be = bn_b[o], mn = bn_m[o], vr = bn_v[o];
        const float inv = sqrtf(vr + 1e-5f);
        float mx = -3.402823466e+38f;
#pragma unroll
        for (int k = 0; k < Kn; ++k) {
            float z = acc[j][k] + bias;
            float y = g * (z - mn) / inv + be;
            y = fmaxf(y, 0.0f);              // ReLU before max, literal order
            mx = fmaxf(mx, y);
        }
        out_feat[(size_t)bs * COUTn + o] = mx;
    }
}

extern "C" void kernel_launch(void* const* d_in, const int* in_sizes, int n_in,
                              void* d_out, int out_size, void* d_ws, size_t ws_size,
                              hipStream_t stream) {
    const float* xyz    = (const float*)d_in[0];
    const float* feat   = (const float*)d_in[1];
    const float* conv_w = (const float*)d_in[2];
    const float* conv_b = (const float*)d_in[3];
    const float* bn_g   = (const float*)d_in[4];
    const float* bn_b   = (const float*)d_in[5];
    const float* bn_m   = (const float*)d_in[6];
    const float* bn_v   = (const float*)d_in[7];

    float* out_xyz  = (float*)d_out;
    float* out_feat = out_xyz + (size_t)Bn * Sn * 3;

    // no workspace usage
    k_fps <<<dim3(Bn),            dim3(256),  0, stream>>>(xyz, out_xyz);
    k_feat<<<dim3(Bn * Sn / 16),  dim3(1024), 0, stream>>>(xyz, out_xyz, feat,
                                                           conv_w, conv_b,
                                                           bn_g, bn_b, bn_m, bn_v,
                                                           out_feat);
}